// Round 1
// baseline (801.014 us; speedup 1.0000x reference)
//
#include <hip/hip_runtime.h>
#include <math.h>

#define NT 1024
#define CD 2
#define DD 1024
#define GG 16
#define LOG1E6 -13.8155105579642740f
#define NEG_BIG -1e30f

// ---------------------------------------------------------------------------
// K1: fp32 GEMM  P_z[r][e] = sum_d A[r][d] * W_z[e][d] + b_z[e]
//     A row r=(c,n): f_a[(n*CD+c)*DD],  z in {Q, K, V(conv)}
//     64x64 tile, K-step 32, 256 threads, 4x4 micro-tile
// ---------------------------------------------------------------------------
__global__ __launch_bounds__(256) void k1_proj(
    const float* __restrict__ fa,
    const float* __restrict__ Wq, const float* __restrict__ bq,
    const float* __restrict__ Wk, const float* __restrict__ bk,
    const float* __restrict__ Wc, const float* __restrict__ bc,
    float* __restrict__ Qo, float* __restrict__ Ko, float* __restrict__ Vo)
{
    const int et = blockIdx.x, rt = blockIdx.y, z = blockIdx.z;
    const float* W  = (z == 0) ? Wq : (z == 1) ? Wk : Wc;
    const float* bb = (z == 0) ? bq : (z == 1) ? bk : bc;
    float* Out      = (z == 0) ? Qo : (z == 1) ? Ko : Vo;

    __shared__ float Al[32][68];   // [d][r], padded
    __shared__ float Wl[32][68];   // [d][e], padded

    const int t  = threadIdx.x;
    const int tx = t & 15, ty = t >> 4;   // compute mapping (e, r)
    const int dd = t & 7,  rr = t >> 3;   // load mapping
    const int r0 = rt * 64, e0 = et * 64;

    float acc[4][4];
    #pragma unroll
    for (int a = 0; a < 4; ++a)
        #pragma unroll
        for (int b = 0; b < 4; ++b) acc[a][b] = 0.f;

    for (int kt = 0; kt < 32; ++kt) {
        const int db = kt * 32 + dd * 4;
        #pragma unroll
        for (int p = 0; p < 2; ++p) {
            const int row = rr + p * 32;
            const int r = r0 + row;
            const int n = r & (NT - 1), c = r >> 10;
            float4 a4 = *(const float4*)&fa[((size_t)(n * CD + c)) * DD + db];
            Al[dd*4+0][row] = a4.x; Al[dd*4+1][row] = a4.y;
            Al[dd*4+2][row] = a4.z; Al[dd*4+3][row] = a4.w;
            const int e = e0 + row;
            float4 w4 = *(const float4*)&W[((size_t)e) * DD + db];
            Wl[dd*4+0][row] = w4.x; Wl[dd*4+1][row] = w4.y;
            Wl[dd*4+2][row] = w4.z; Wl[dd*4+3][row] = w4.w;
        }
        __syncthreads();
        #pragma unroll
        for (int d = 0; d < 32; ++d) {
            float4 a4 = *(const float4*)&Al[d][ty * 4];
            float4 w4 = *(const float4*)&Wl[d][tx * 4];
            float av[4] = {a4.x, a4.y, a4.z, a4.w};
            float wv[4] = {w4.x, w4.y, w4.z, w4.w};
            #pragma unroll
            for (int a = 0; a < 4; ++a)
                #pragma unroll
                for (int b = 0; b < 4; ++b) acc[a][b] += av[a] * wv[b];
        }
        __syncthreads();
    }
    float4 b4 = *(const float4*)&bb[e0 + tx * 4];
    #pragma unroll
    for (int a = 0; a < 4; ++a) {
        float4 o;
        o.x = acc[a][0] + b4.x; o.y = acc[a][1] + b4.y;
        o.z = acc[a][2] + b4.z; o.w = acc[a][3] + b4.w;
        *(float4*)&Out[((size_t)(r0 + ty * 4 + a)) * DD + e0 + tx * 4] = o;
    }
}

// ---------------------------------------------------------------------------
// K2a: batched aff[c][g][i][j] = (sum_d Q[c,i,g*64+d] * K[c,j,g*64+d]) / 8
//      one block per (c,g, 64-i-tile, 64-j-tile), K=64 (no k-loop)
// ---------------------------------------------------------------------------
__global__ __launch_bounds__(256) void k2a_aff(
    const float* __restrict__ Q, const float* __restrict__ Km,
    float* __restrict__ aff)
{
    const int jt = blockIdx.x, it = blockIdx.y, cg = blockIdx.z;
    const int c = cg >> 4, g = cg & 15;
    __shared__ float Ql[64][68];   // [d][i]
    __shared__ float Kl[64][68];   // [d][j]
    const int t = threadIdx.x;
    const int dd = t & 15, rr = t >> 4;
    const int i0 = it * 64, j0 = jt * 64;
    #pragma unroll
    for (int p = 0; p < 4; ++p) {
        const int row = rr + p * 16;
        float4 q4 = *(const float4*)&Q[((size_t)(c * NT + i0 + row)) * DD + g * 64 + dd * 4];
        Ql[dd*4+0][row] = q4.x; Ql[dd*4+1][row] = q4.y;
        Ql[dd*4+2][row] = q4.z; Ql[dd*4+3][row] = q4.w;
        float4 k4 = *(const float4*)&Km[((size_t)(c * NT + j0 + row)) * DD + g * 64 + dd * 4];
        Kl[dd*4+0][row] = k4.x; Kl[dd*4+1][row] = k4.y;
        Kl[dd*4+2][row] = k4.z; Kl[dd*4+3][row] = k4.w;
    }
    __syncthreads();
    const int tx = t & 15, ty = t >> 4;
    float acc[4][4];
    #pragma unroll
    for (int a = 0; a < 4; ++a)
        #pragma unroll
        for (int b = 0; b < 4; ++b) acc[a][b] = 0.f;
    #pragma unroll 8
    for (int d = 0; d < 64; ++d) {
        float4 q4 = *(const float4*)&Ql[d][ty * 4];
        float4 k4 = *(const float4*)&Kl[d][tx * 4];
        float qv[4] = {q4.x, q4.y, q4.z, q4.w};
        float kv[4] = {k4.x, k4.y, k4.z, k4.w};
        #pragma unroll
        for (int a = 0; a < 4; ++a)
            #pragma unroll
            for (int b = 0; b < 4; ++b) acc[a][b] += qv[a] * kv[b];
    }
    #pragma unroll
    for (int a = 0; a < 4; ++a) {
        float4 o;
        o.x = acc[a][0] * 0.125f; o.y = acc[a][1] * 0.125f;
        o.z = acc[a][2] * 0.125f; o.w = acc[a][3] * 0.125f;
        *(float4*)&aff[(((size_t)(c * GG + g)) * NT + i0 + ty * 4 + a) * NT + j0 + tx * 4] = o;
    }
}

// ---------------------------------------------------------------------------
// K2b: per block (c, 8-row i-tile): stream pe once, compute w_g logs for all
//      16 g (phase 1), combine with aff + log_iou and maintain per-(i,g)
//      top-10 (phase 2), then softmax + sparse V-gather -> y.
// ---------------------------------------------------------------------------
__global__ __launch_bounds__(256) void k2b_main(
    const float* __restrict__ pe, const float* __restrict__ iou,
    const float* __restrict__ WGw, const float* __restrict__ WGb,
    const float* __restrict__ aff, const float* __restrict__ V,
    float* __restrict__ y)
{
    const int it = blockIdx.x, c = blockIdx.y;
    const int i0 = it * 8;
    __shared__ float wgw[16][64];
    __shared__ float wgb[16];
    __shared__ float wgl[64][8][17];   // [j][i][g], padded to kill bank conflicts

    const int t = threadIdx.x;
    ((float4*)&wgw[0][0])[t] = ((const float4*)WGw)[t];   // 1024 floats
    if (t < 16) wgb[t] = WGb[t];
    __syncthreads();

    float tv[10]; int tidx[10];
    #pragma unroll
    for (int q = 0; q < 10; ++q) { tv[q] = NEG_BIG; tidx[q] = 0; }

    const int p_i = t >> 5, p_jb = t & 31;      // phase-1 mapping: (i, 2-j group)
    const int s_i = (t >> 4) & 7, s_g = t & 15; // phase-2 mapping (t < 128)

    for (int jt = 0; jt < 16; ++jt) {
        const int j0 = jt * 64;
        // ---- phase 1: w_g = relu(pe . WGw^T + b) -> log(clip) into LDS ----
        float acc[2][16];
        #pragma unroll
        for (int g = 0; g < 16; ++g) { acc[0][g] = wgb[g]; acc[1][g] = wgb[g]; }
        const float* pr = &pe[(((size_t)c * NT + (i0 + p_i)) * NT + (j0 + p_jb * 2)) * 64];
        #pragma unroll 4
        for (int d = 0; d < 64; d += 4) {
            float4 p0 = *(const float4*)&pr[d];
            float4 p1 = *(const float4*)&pr[64 + d];
            float a0[4] = {p0.x, p0.y, p0.z, p0.w};
            float a1[4] = {p1.x, p1.y, p1.z, p1.w};
            #pragma unroll
            for (int g = 0; g < 16; ++g) {
                float4 w4 = *(const float4*)&wgw[g][d];
                float wv[4] = {w4.x, w4.y, w4.z, w4.w};
                #pragma unroll
                for (int q = 0; q < 4; ++q) {
                    acc[0][g] += a0[q] * wv[q];
                    acc[1][g] += a1[q] * wv[q];
                }
            }
        }
        #pragma unroll
        for (int jj = 0; jj < 2; ++jj) {
            #pragma unroll
            for (int g = 0; g < 16; ++g) {
                const float v = acc[jj][g];
                wgl[p_jb * 2 + jj][p_i][g] = (v > 1e-6f) ? __logf(v) : LOG1E6;
            }
        }
        __syncthreads();
        // ---- phase 2: w_mn = log(wg) + aff + log_iou ; top-10 scan ----
        if (t < 128) {
            const float* ar   = &aff[(((size_t)(c * GG + s_g)) * NT + (i0 + s_i)) * NT + j0];
            const float* orow = &iou[((size_t)c * NT + (i0 + s_i)) * NT + j0];
            #pragma unroll 2
            for (int j4 = 0; j4 < 64; j4 += 4) {
                float4 a4 = *(const float4*)&ar[j4];
                float4 o4 = *(const float4*)&orow[j4];
                float av[4] = {a4.x, a4.y, a4.z, a4.w};
                float ov[4] = {o4.x, o4.y, o4.z, o4.w};
                #pragma unroll
                for (int q = 0; q < 4; ++q) {
                    const int j = j4 + q;
                    const float val = wgl[j][s_i][s_g] + av[q]
                                    + ((ov[q] >= 1e-6f) ? 0.f : LOG1E6);
                    if (val > tv[0]) {   // rare (~4.6%) divergent insert
                        const int ix = j0 + j;
                        #pragma unroll
                        for (int s = 0; s < 10; ++s) {
                            const bool up   = (s < 9) ? (val > tv[s + 1]) : false;
                            const bool here = (val > tv[s]);
                            const float ntv = up ? tv[s + 1] : (here ? val : tv[s]);
                            const int   nti = up ? tidx[s + 1] : (here ? ix : tidx[s]);
                            tv[s] = ntv; tidx[s] = nti;
                        }
                    }
                }
            }
        }
        __syncthreads();
    }

    // ---- finalize: softmax over top-10, gather V rows, write y ----
    if (t < 128) {
        const float m = tv[9];
        float w[10]; float s = 0.f;
        #pragma unroll
        for (int q = 0; q < 10; ++q) { w[q] = __expf(tv[q] - m); s += w[q]; }
        const float inv = 1.f / s;
        #pragma unroll
        for (int q = 0; q < 10; ++q) w[q] *= inv;
        const float* vb[10];
        #pragma unroll
        for (int q = 0; q < 10; ++q)
            vb[q] = &V[((size_t)(c * NT + tidx[q])) * DD + s_g * 64];
        float* yo = &y[((size_t)(i0 + s_i) * CD + c) * DD + s_g * 64];
        #pragma unroll 4
        for (int ot = 0; ot < 16; ++ot) {
            float4 o = {0.f, 0.f, 0.f, 0.f};
            #pragma unroll
            for (int q = 0; q < 10; ++q) {
                float4 v4 = *(const float4*)&vb[q][ot * 4];
                o.x += w[q] * v4.x; o.y += w[q] * v4.y;
                o.z += w[q] * v4.z; o.w += w[q] * v4.w;
            }
            *(float4*)&yo[ot * 4] = o;
        }
    }
}

extern "C" void kernel_launch(void* const* d_in, const int* in_sizes, int n_in,
                              void* d_out, int out_size, void* d_ws, size_t ws_size,
                              hipStream_t stream) {
    (void)in_sizes; (void)n_in; (void)out_size; (void)ws_size;
    const float* f_a = (const float*)d_in[0];
    const float* pe  = (const float*)d_in[1];
    const float* iou = (const float*)d_in[2];
    const float* WGw = (const float*)d_in[3];
    const float* WGb = (const float*)d_in[4];
    const float* WKw = (const float*)d_in[5];
    const float* WKb = (const float*)d_in[6];
    const float* WQw = (const float*)d_in[7];
    const float* WQb = (const float*)d_in[8];
    const float* Cw  = (const float*)d_in[9];
    const float* Cb  = (const float*)d_in[10];
    float* yout = (float*)d_out;

    // workspace layout (floats): Q [2M] | K [2M] | V [2M] | aff [33.55M]  ~159.4 MB
    float* ws  = (float*)d_ws;
    float* Q   = ws;
    float* Kp  = ws + (1u << 21);
    float* V   = ws + (2u << 21);
    float* aff = ws + (3u << 21);

    k1_proj<<<dim3(16, 32, 3), 256, 0, stream>>>(f_a, WQw, WQb, WKw, WKb, Cw, Cb, Q, Kp, V);
    k2a_aff<<<dim3(16, 16, 32), 256, 0, stream>>>(Q, Kp, aff);
    k2b_main<<<dim3(128, 2), 256, 0, stream>>>(pe, iou, WGw, WGb, aff, V, yout);
}

// Round 2
// 738.028 us; speedup vs baseline: 1.0853x; 1.0853x over previous
//
#include <hip/hip_runtime.h>
#include <math.h>

#define NT 1024
#define CD 2
#define DD 1024
#define GG 16
#define LOG1E6 -13.8155105579642740f
#define NEG_BIG -1e30f

// ---------------------------------------------------------------------------
// K1: fp32 GEMM  P_z[r][e] = sum_d A[r][d] * W_z[e][d] + b_z[e]
//     tile 128 rows x 64 cols, BK=32, 256 threads, 8x4 micro-tile
//     grid (16 e-tiles, 16 r-tiles, 3 z) = 768 blocks = exactly 3/CU
// ---------------------------------------------------------------------------
__global__ __launch_bounds__(256) void k1_proj(
    const float* __restrict__ fa,
    const float* __restrict__ Wq, const float* __restrict__ bq,
    const float* __restrict__ Wk, const float* __restrict__ bk,
    const float* __restrict__ Wc, const float* __restrict__ bc,
    float* __restrict__ Qo, float* __restrict__ Ko, float* __restrict__ Vo)
{
    const int et = blockIdx.x, rt = blockIdx.y, z = blockIdx.z;
    const float* W  = (z == 0) ? Wq : (z == 1) ? Wk : Wc;
    const float* bb = (z == 0) ? bq : (z == 1) ? bk : bc;
    float* Out      = (z == 0) ? Qo : (z == 1) ? Ko : Vo;

    __shared__ float Al[32][132];   // [d][r], 128 rows + pad
    __shared__ float Wl[32][68];    // [d][e], 64 cols + pad

    const int t  = threadIdx.x;
    const int tx = t & 15, ty = t >> 4;   // compute: e-quad, r-octet
    const int dd = t & 7,  rr = t >> 3;   // load mapping
    const int r0 = rt * 128, e0 = et * 64;

    float acc[8][4];
    #pragma unroll
    for (int a = 0; a < 8; ++a)
        #pragma unroll
        for (int b = 0; b < 4; ++b) acc[a][b] = 0.f;

    for (int kt = 0; kt < 32; ++kt) {
        const int db = kt * 32 + dd * 4;
        #pragma unroll
        for (int p = 0; p < 4; ++p) {
            const int row = rr + p * 32;
            const int r = r0 + row;
            const int n = r & (NT - 1), c = r >> 10;
            float4 a4 = *(const float4*)&fa[((size_t)(n * CD + c)) * DD + db];
            Al[dd*4+0][row] = a4.x; Al[dd*4+1][row] = a4.y;
            Al[dd*4+2][row] = a4.z; Al[dd*4+3][row] = a4.w;
        }
        #pragma unroll
        for (int p = 0; p < 2; ++p) {
            const int erow = rr + p * 32;
            float4 w4 = *(const float4*)&W[((size_t)(e0 + erow)) * DD + db];
            Wl[dd*4+0][erow] = w4.x; Wl[dd*4+1][erow] = w4.y;
            Wl[dd*4+2][erow] = w4.z; Wl[dd*4+3][erow] = w4.w;
        }
        __syncthreads();
        #pragma unroll 4
        for (int d = 0; d < 32; ++d) {
            float4 a0 = *(const float4*)&Al[d][ty * 8];
            float4 a1 = *(const float4*)&Al[d][ty * 8 + 4];
            float4 w4 = *(const float4*)&Wl[d][tx * 4];
            float av[8] = {a0.x, a0.y, a0.z, a0.w, a1.x, a1.y, a1.z, a1.w};
            float wv[4] = {w4.x, w4.y, w4.z, w4.w};
            #pragma unroll
            for (int a = 0; a < 8; ++a)
                #pragma unroll
                for (int b = 0; b < 4; ++b) acc[a][b] += av[a] * wv[b];
        }
        __syncthreads();
    }
    float4 b4 = *(const float4*)&bb[e0 + tx * 4];
    #pragma unroll
    for (int a = 0; a < 8; ++a) {
        float4 o;
        o.x = acc[a][0] + b4.x; o.y = acc[a][1] + b4.y;
        o.z = acc[a][2] + b4.z; o.w = acc[a][3] + b4.w;
        *(float4*)&Out[((size_t)(r0 + ty * 8 + a)) * DD + e0 + tx * 4] = o;
    }
}

// ---------------------------------------------------------------------------
// K2a: aff[c][g][i][j] = (sum_d Q[c,i,g*64+d] * K[c,j,g*64+d]) / 8
// ---------------------------------------------------------------------------
__global__ __launch_bounds__(256) void k2a_aff(
    const float* __restrict__ Q, const float* __restrict__ Km,
    float* __restrict__ aff)
{
    const int jt = blockIdx.x, it = blockIdx.y, cg = blockIdx.z;
    const int c = cg >> 4, g = cg & 15;
    __shared__ float Ql[64][68];   // [d][i]
    __shared__ float Kl[64][68];   // [d][j]
    const int t = threadIdx.x;
    const int dd = t & 15, rr = t >> 4;
    const int i0 = it * 64, j0 = jt * 64;
    #pragma unroll
    for (int p = 0; p < 4; ++p) {
        const int row = rr + p * 16;
        float4 q4 = *(const float4*)&Q[((size_t)(c * NT + i0 + row)) * DD + g * 64 + dd * 4];
        Ql[dd*4+0][row] = q4.x; Ql[dd*4+1][row] = q4.y;
        Ql[dd*4+2][row] = q4.z; Ql[dd*4+3][row] = q4.w;
        float4 k4 = *(const float4*)&Km[((size_t)(c * NT + j0 + row)) * DD + g * 64 + dd * 4];
        Kl[dd*4+0][row] = k4.x; Kl[dd*4+1][row] = k4.y;
        Kl[dd*4+2][row] = k4.z; Kl[dd*4+3][row] = k4.w;
    }
    __syncthreads();
    const int tx = t & 15, ty = t >> 4;
    float acc[4][4];
    #pragma unroll
    for (int a = 0; a < 4; ++a)
        #pragma unroll
        for (int b = 0; b < 4; ++b) acc[a][b] = 0.f;
    #pragma unroll 8
    for (int d = 0; d < 64; ++d) {
        float4 q4 = *(const float4*)&Ql[d][ty * 4];
        float4 k4 = *(const float4*)&Kl[d][tx * 4];
        float qv[4] = {q4.x, q4.y, q4.z, q4.w};
        float kv[4] = {k4.x, k4.y, k4.z, k4.w};
        #pragma unroll
        for (int a = 0; a < 4; ++a)
            #pragma unroll
            for (int b = 0; b < 4; ++b) acc[a][b] += qv[a] * kv[b];
    }
    #pragma unroll
    for (int a = 0; a < 4; ++a) {
        float4 o;
        o.x = acc[a][0] * 0.125f; o.y = acc[a][1] * 0.125f;
        o.z = acc[a][2] * 0.125f; o.w = acc[a][3] * 0.125f;
        *(float4*)&aff[(((size_t)(c * GG + g)) * NT + i0 + ty * 4 + a) * NT + j0 + tx * 4] = o;
    }
}

// ---------------------------------------------------------------------------
// K2b1: chunked scan. Block = (j-chunk of 256, 8-row i-tile, c).
//       Phase 1: w_g GEMM -> log -> LDS (conflict-free layout).
//       Phase 2: w_mn = log(wg)+aff+log_iou, per-(i,g) top-10 in regs.
//       Writes 10 candidates per (c,i,g,chunk) to ws.
// ---------------------------------------------------------------------------
__global__ __launch_bounds__(256) void k2b1_scan(
    const float* __restrict__ pe, const float* __restrict__ iou,
    const float* __restrict__ WGw, const float* __restrict__ WGb,
    const float* __restrict__ aff,
    float* __restrict__ cv, int* __restrict__ ci)
{
    const int ch = blockIdx.x;   // 0..3  (256 j each)
    const int it = blockIdx.y;   // 0..127 (8 i each)
    const int c  = blockIdx.z;
    const int i0 = it * 8;

    __shared__ float wgw[16][64];
    __shared__ float wgb_s[16];
    __shared__ float wgl[8][16][65];   // [i][g][j], pad 65: <=2 lanes/bank

    const int t = threadIdx.x;
    ((float4*)&wgw[0][0])[t] = ((const float4*)WGw)[t];   // 1024 floats
    if (t < 16) wgb_s[t] = WGb[t];
    __syncthreads();

    float tv[10]; int tidx[10];
    #pragma unroll
    for (int q = 0; q < 10; ++q) { tv[q] = NEG_BIG; tidx[q] = 0; }

    const int p_i = t >> 5;             // phase-1: i row (8)
    const int gh  = (t >> 4) & 1;       // phase-1: g half (8 g each)
    const int jq  = t & 15;             // phase-1: j = jq + jj*16
    const int s_i = (t >> 4) & 7, s_g = t & 15;   // phase-2 (t < 128)

    for (int jt = 0; jt < 4; ++jt) {
        const int j0 = ch * 256 + jt * 64;
        // ---- phase 1: 4 j x 8 g per thread ----
        float acc[4][8];
        #pragma unroll
        for (int g = 0; g < 8; ++g) {
            const float b = wgb_s[gh * 8 + g];
            #pragma unroll
            for (int jj = 0; jj < 4; ++jj) acc[jj][g] = b;
        }
        const float* pr = &pe[(((size_t)c * NT + (i0 + p_i)) * NT + j0 + jq) * 64];
        #pragma unroll 2
        for (int d = 0; d < 64; d += 4) {
            float4 p4[4];
            #pragma unroll
            for (int jj = 0; jj < 4; ++jj)
                p4[jj] = *(const float4*)&pr[jj * (16 * 64) + d];
            #pragma unroll
            for (int g = 0; g < 8; ++g) {
                float4 w4 = *(const float4*)&wgw[gh * 8 + g][d];
                #pragma unroll
                for (int jj = 0; jj < 4; ++jj) {
                    acc[jj][g] += p4[jj].x * w4.x + p4[jj].y * w4.y
                                + p4[jj].z * w4.z + p4[jj].w * w4.w;
                }
            }
        }
        #pragma unroll
        for (int g = 0; g < 8; ++g)
            #pragma unroll
            for (int jj = 0; jj < 4; ++jj) {
                const float v = acc[jj][g];
                wgl[p_i][gh * 8 + g][jq + jj * 16] = (v > 1e-6f) ? __logf(v) : LOG1E6;
            }
        __syncthreads();
        // ---- phase 2: scan 64 j, top-10 ----
        if (t < 128) {
            const float* ar   = &aff[(((size_t)(c * GG + s_g)) * NT + (i0 + s_i)) * NT + j0];
            const float* orow = &iou[((size_t)c * NT + (i0 + s_i)) * NT + j0];
            const float* wl   = &wgl[s_i][s_g][0];
            #pragma unroll 2
            for (int j4 = 0; j4 < 64; j4 += 4) {
                float4 a4 = *(const float4*)&ar[j4];
                float4 o4 = *(const float4*)&orow[j4];
                float av[4] = {a4.x, a4.y, a4.z, a4.w};
                float ov[4] = {o4.x, o4.y, o4.z, o4.w};
                #pragma unroll
                for (int q = 0; q < 4; ++q) {
                    const int j = j4 + q;
                    const float val = wl[j] + av[q] + ((ov[q] >= 1e-6f) ? 0.f : LOG1E6);
                    if (val > tv[0]) {
                        const int ix = j0 + j;
                        #pragma unroll
                        for (int s = 0; s < 10; ++s) {
                            const bool up   = (s < 9) ? (val > tv[s + 1]) : false;
                            const bool here = (val > tv[s]);
                            const float ntv = up ? tv[s + 1] : (here ? val : tv[s]);
                            const int   nti = up ? tidx[s + 1] : (here ? ix : tidx[s]);
                            tv[s] = ntv; tidx[s] = nti;
                        }
                    }
                }
            }
        }
        __syncthreads();
    }
    if (t < 128) {
        const size_t base = ((((size_t)c * NT + (i0 + s_i)) * GG + s_g) * 4 + ch) * 10;
        #pragma unroll
        for (int q = 0; q < 10; ++q) { cv[base + q] = tv[q]; ci[base + q] = tidx[q]; }
    }
}

// ---------------------------------------------------------------------------
// K2b2: one 64-lane wave per (c,i,g) row. All lanes redundantly merge the
//       4x10 chunk candidates -> global top-10, softmax, then coalesced
//       V-gather: lane = output dim within the 64-wide g-slice.
// ---------------------------------------------------------------------------
__global__ __launch_bounds__(256) void k2b2_fin(
    const float* __restrict__ cv, const int* __restrict__ ci,
    const float* __restrict__ V, float* __restrict__ y)
{
    const int w    = (blockIdx.x << 2) + (threadIdx.x >> 6);  // row id
    const int lane = threadIdx.x & 63;
    const int c = w >> 14;            // w = (c*NT + i)*GG + g
    const int i = (w >> 4) & (NT - 1);
    const int g = w & 15;

    float tv[10]; int tidx[10];
    #pragma unroll
    for (int q = 0; q < 10; ++q) { tv[q] = NEG_BIG; tidx[q] = 0; }

    const size_t base = (size_t)w * 40;
    for (int q = 0; q < 40; ++q) {           // chunk-ascending: tie order ok
        const float val = cv[base + q];
        const int   ix  = ci[base + q];
        if (val > tv[0]) {
            #pragma unroll
            for (int s = 0; s < 10; ++s) {
                const bool up   = (s < 9) ? (val > tv[s + 1]) : false;
                const bool here = (val > tv[s]);
                const float ntv = up ? tv[s + 1] : (here ? val : tv[s]);
                const int   nti = up ? tidx[s + 1] : (here ? ix : tidx[s]);
                tv[s] = ntv; tidx[s] = nti;
            }
        }
    }
    const float m = tv[9];
    float wgt[10]; float s = 0.f;
    #pragma unroll
    for (int q = 0; q < 10; ++q) { wgt[q] = __expf(tv[q] - m); s += wgt[q]; }
    const float inv = 1.f / s;
    float o = 0.f;
    #pragma unroll
    for (int q = 0; q < 10; ++q)
        o += (wgt[q] * inv) * V[((size_t)(c * NT + tidx[q])) * DD + g * 64 + lane];
    y[((size_t)i * CD + c) * DD + g * 64 + lane] = o;
}

extern "C" void kernel_launch(void* const* d_in, const int* in_sizes, int n_in,
                              void* d_out, int out_size, void* d_ws, size_t ws_size,
                              hipStream_t stream) {
    (void)in_sizes; (void)n_in; (void)out_size; (void)ws_size;
    const float* f_a = (const float*)d_in[0];
    const float* pe  = (const float*)d_in[1];
    const float* iou = (const float*)d_in[2];
    const float* WGw = (const float*)d_in[3];
    const float* WGb = (const float*)d_in[4];
    const float* WKw = (const float*)d_in[5];
    const float* WKb = (const float*)d_in[6];
    const float* WQw = (const float*)d_in[7];
    const float* WQb = (const float*)d_in[8];
    const float* Cw  = (const float*)d_in[9];
    const float* Cb  = (const float*)d_in[10];
    float* yout = (float*)d_out;

    // ws floats: Q [2^21] | K [2^21] | V [2^21] | aff [2^25]   (~159.4 MB)
    // After k2a, Q/K are dead -> candidate buffers overlay them:
    //   cv (1.31M floats) on Q region, ci (1.31M ints) on K region.
    float* ws  = (float*)d_ws;
    float* Q   = ws;
    float* Kp  = ws + (1u << 21);
    float* V   = ws + (2u << 21);
    float* aff = ws + (3u << 21);
    float* cv  = ws;                      // overlay Q
    int*   ci  = (int*)(ws + (1u << 21)); // overlay K

    k1_proj<<<dim3(16, 16, 3), 256, 0, stream>>>(f_a, WQw, WQb, WKw, WKb, Cw, Cb, Q, Kp, V);
    k2a_aff<<<dim3(16, 16, 32), 256, 0, stream>>>(Q, Kp, aff);
    k2b1_scan<<<dim3(4, 128, 2), 256, 0, stream>>>(pe, iou, WGw, WGb, aff, cv, ci);
    k2b2_fin<<<8192, 256, 0, stream>>>(cv, ci, V, yout);
}